// Round 1
// baseline (656.954 us; speedup 1.0000x reference)
//
#include <hip/hip_runtime.h>

// Problem constants: B=8, C=128, H=96, W=96, D=4
// hs layout (ws):  [b][d][h][w][c] bf16
// hid layout (ws): [b][d][w][h][c] bf16  (reuses xT buffer; xT dead after row kernel)
// xT layout (ws):  [b][d][h][w][c] bf16

typedef short bf16x8 __attribute__((ext_vector_type(8)));
typedef short short4v __attribute__((ext_vector_type(4)));
typedef float f32x4 __attribute__((ext_vector_type(4)));

__device__ __forceinline__ unsigned short f2bf(float f) {
  unsigned int u = __builtin_bit_cast(unsigned int, f);
  u = (u + 0x7FFFu + ((u >> 16) & 1u)) >> 16;
  return (unsigned short)u;
}
__device__ __forceinline__ float bf2f(unsigned short h) {
  unsigned int u = ((unsigned int)h) << 16;
  return __builtin_bit_cast(float, u);
}

// ---------------- prep: cast weights to bf16, sum biases ----------------
__global__ __launch_bounds__(256) void prep_kernel(
    const float* __restrict__ W1, const float* __restrict__ b1,
    const float* __restrict__ W2, const float* __restrict__ b2,
    const float* __restrict__ W4, const float* __restrict__ b4,
    const float* __restrict__ W5, const float* __restrict__ b5,
    unsigned short* __restrict__ Wb, float* __restrict__ bs12,
    float* __restrict__ bs45) {
  int gid = blockIdx.x * 256 + threadIdx.x;
  if (gid < 4 * 65536) {
    int m = gid >> 16;
    int r = gid & 65535;
    const float* src = (m == 0) ? W1 : (m == 1) ? W2 : (m == 2) ? W4 : W5;
    Wb[m * 65536 + r] = f2bf(src[r]);
  } else if (gid < 4 * 65536 + 512) {
    int r = gid - 4 * 65536;
    bs12[r] = b1[r] + b2[r];
  } else if (gid < 4 * 65536 + 1024) {
    int r = gid - 4 * 65536 - 512;
    bs45[r] = b4[r] + b5[r];
  }
}

// ---------------- transpose x -> xT bf16 [b][d][h][w][c] ----------------
__global__ __launch_bounds__(256) void transpose_kernel(
    const float* __restrict__ x, unsigned short* __restrict__ xT) {
  __shared__ float tile[384 * 33];
  int bid = blockIdx.x;
  int cc = bid & 3;
  int rest = bid >> 2;
  int h = rest % 96;
  int b = rest / 96;
  int c0 = cc * 32;
  int tid = threadIdx.x;
  // read x[b][c0+c][h][w][d], coalesced over (w,d)
  for (int idx = tid; idx < 32 * 384; idx += 256) {
    int c = idx / 384;
    int wd = idx % 384;
    float v = x[((size_t)(b * 128 + c0 + c) * 96 + h) * 384 + wd];
    tile[wd * 33 + c] = v;
  }
  __syncthreads();
  // write xT[b][d][h][w][c0+i], runs of 32 bf16 per (d,w)
  for (int idx = tid; idx < 32 * 384; idx += 256) {
    int i = idx & 31;
    int q = idx >> 5;
    int d = q / 96;
    int w = q % 96;
    float v = tile[(w * 4 + d) * 33 + i];
    xT[(((size_t)(b * 4 + d) * 96 + h) * 96 + w) * 128 + c0 + i] = f2bf(v);
  }
}

// ---------------- row scan: hs = scan_h(relu(W1 x_h + W2 prev + b)) ----------------
__global__ __launch_bounds__(256) void row_kernel(
    const unsigned short* __restrict__ xT, unsigned short* __restrict__ hs,
    const unsigned short* __restrict__ Wb, const float* __restrict__ bs12) {
  int bid = blockIdx.x;
  int wt = bid % 6;
  int bd = bid / 6;  // b*4+d
  int d = bd & 3;
  int w0 = wt * 16;
  int tid = threadIdx.x;
  int lane = tid & 63;
  int wave = tid >> 6;
  int quad = lane >> 4;
  int n = lane & 15;

  __shared__ unsigned short prevs[16 * 136];  // [w_local][c] padded stride

  const unsigned short* w1p = Wb + 0 * 65536 + d * 16384;
  const unsigned short* w2p = Wb + 1 * 65536 + d * 16384;

  bf16x8 A1[2][4], A2[2][4];
#pragma unroll
  for (int mi = 0; mi < 2; ++mi) {
    int c = (wave * 2 + mi) * 16 + n;
#pragma unroll
    for (int kt = 0; kt < 4; ++kt) {
      int k0 = kt * 32 + quad * 8;
      A1[mi][kt] = *(const bf16x8*)(w1p + c * 128 + k0);
      A2[mi][kt] = *(const bf16x8*)(w2p + c * 128 + k0);
    }
  }
  float bias[2][4];
#pragma unroll
  for (int mi = 0; mi < 2; ++mi)
#pragma unroll
    for (int r = 0; r < 4; ++r)
      bias[mi][r] = bs12[d * 128 + (wave * 2 + mi) * 16 + quad * 4 + r];

  size_t bd9216 = (size_t)bd * 9216;

  // h = 0: hs row 0 = x row 0 (raw); also seed prev
  {
    int wl = tid >> 4;
    int c8 = (tid & 15) * 8;
    bf16x8 v = *(const bf16x8*)(xT + (bd9216 + (size_t)(w0 + wl)) * 128 + c8);
    *(bf16x8*)&prevs[wl * 136 + c8] = v;
    *(bf16x8*)(hs + (bd9216 + (size_t)(w0 + wl)) * 128 + c8) = v;
  }
  __syncthreads();

  for (int h = 1; h < 96; ++h) {
    bf16x8 Bx[4], Bp[4];
    const unsigned short* xrow = xT + (bd9216 + (size_t)h * 96 + w0 + n) * 128;
#pragma unroll
    for (int kt = 0; kt < 4; ++kt) {
      int k0 = kt * 32 + quad * 8;
      Bp[kt] = *(const bf16x8*)&prevs[n * 136 + k0];
      Bx[kt] = *(const bf16x8*)(xrow + k0);
    }
    __syncthreads();  // all reads of prevs done before overwrite
    f32x4 acc[2];
#pragma unroll
    for (int mi = 0; mi < 2; ++mi) {
      f32x4 a;
      a[0] = bias[mi][0]; a[1] = bias[mi][1]; a[2] = bias[mi][2]; a[3] = bias[mi][3];
      acc[mi] = a;
    }
#pragma unroll
    for (int kt = 0; kt < 4; ++kt) {
      acc[0] = __builtin_amdgcn_mfma_f32_16x16x32_bf16(A1[0][kt], Bx[kt], acc[0], 0, 0, 0);
      acc[1] = __builtin_amdgcn_mfma_f32_16x16x32_bf16(A1[1][kt], Bx[kt], acc[1], 0, 0, 0);
      acc[0] = __builtin_amdgcn_mfma_f32_16x16x32_bf16(A2[0][kt], Bp[kt], acc[0], 0, 0, 0);
      acc[1] = __builtin_amdgcn_mfma_f32_16x16x32_bf16(A2[1][kt], Bp[kt], acc[1], 0, 0, 0);
    }
    unsigned short* hrow = hs + (bd9216 + (size_t)h * 96 + w0 + n) * 128;
#pragma unroll
    for (int mi = 0; mi < 2; ++mi) {
      short4v pk;
#pragma unroll
      for (int r = 0; r < 4; ++r) {
        float v = acc[mi][r];
        v = v > 0.f ? v : 0.f;
        pk[r] = (short)f2bf(v);
      }
      int coff = (wave * 2 + mi) * 16 + quad * 4;
      *(short4v*)&prevs[n * 136 + coff] = pk;
      *(short4v*)(hrow + coff) = pk;
    }
    __syncthreads();
  }
}

// ---------------- col scan: hid = scan_w(relu(W4 hs_w + W5 prev + b)) ----------------
__global__ __launch_bounds__(256) void col_kernel(
    const unsigned short* __restrict__ hs, unsigned short* __restrict__ hid,
    const unsigned short* __restrict__ Wb, const float* __restrict__ bs45) {
  int bid = blockIdx.x;
  int ht = bid % 6;
  int bd = bid / 6;
  int d = bd & 3;
  int h0 = ht * 16;
  int tid = threadIdx.x;
  int lane = tid & 63;
  int wave = tid >> 6;
  int quad = lane >> 4;
  int n = lane & 15;

  __shared__ unsigned short prevs[16 * 136];  // [h_local][c]

  const unsigned short* w4p = Wb + 2 * 65536 + d * 16384;
  const unsigned short* w5p = Wb + 3 * 65536 + d * 16384;

  bf16x8 A4[2][4], A5[2][4];
#pragma unroll
  for (int mi = 0; mi < 2; ++mi) {
    int c = (wave * 2 + mi) * 16 + n;
#pragma unroll
    for (int kt = 0; kt < 4; ++kt) {
      int k0 = kt * 32 + quad * 8;
      A4[mi][kt] = *(const bf16x8*)(w4p + c * 128 + k0);
      A5[mi][kt] = *(const bf16x8*)(w5p + c * 128 + k0);
    }
  }
  float bias[2][4];
#pragma unroll
  for (int mi = 0; mi < 2; ++mi)
#pragma unroll
    for (int r = 0; r < 4; ++r)
      bias[mi][r] = bs45[d * 128 + (wave * 2 + mi) * 16 + quad * 4 + r];

  size_t bd9216 = (size_t)bd * 9216;

  // w = 0: hid col 0 = relu(hs col 0); seed prev
  {
    int hl = tid >> 4;
    int c8 = (tid & 15) * 8;
    bf16x8 v = *(const bf16x8*)(hs + (bd9216 + (size_t)(h0 + hl) * 96) * 128 + c8);
#pragma unroll
    for (int j = 0; j < 8; ++j) {
      unsigned short uv = (unsigned short)v[j];
      if (uv & 0x8000u) v[j] = 0;  // bf16 relu
    }
    *(bf16x8*)&prevs[hl * 136 + c8] = v;
    *(bf16x8*)(hid + (bd9216 + (size_t)(h0 + hl)) * 128 + c8) = v;
  }
  __syncthreads();

  for (int w = 1; w < 96; ++w) {
    bf16x8 Bh[4], Bp[4];
    const unsigned short* hcol = hs + (bd9216 + (size_t)(h0 + n) * 96 + w) * 128;
#pragma unroll
    for (int kt = 0; kt < 4; ++kt) {
      int k0 = kt * 32 + quad * 8;
      Bp[kt] = *(const bf16x8*)&prevs[n * 136 + k0];
      Bh[kt] = *(const bf16x8*)(hcol + k0);
    }
    __syncthreads();
    f32x4 acc[2];
#pragma unroll
    for (int mi = 0; mi < 2; ++mi) {
      f32x4 a;
      a[0] = bias[mi][0]; a[1] = bias[mi][1]; a[2] = bias[mi][2]; a[3] = bias[mi][3];
      acc[mi] = a;
    }
#pragma unroll
    for (int kt = 0; kt < 4; ++kt) {
      acc[0] = __builtin_amdgcn_mfma_f32_16x16x32_bf16(A4[0][kt], Bh[kt], acc[0], 0, 0, 0);
      acc[1] = __builtin_amdgcn_mfma_f32_16x16x32_bf16(A4[1][kt], Bh[kt], acc[1], 0, 0, 0);
      acc[0] = __builtin_amdgcn_mfma_f32_16x16x32_bf16(A5[0][kt], Bp[kt], acc[0], 0, 0, 0);
      acc[1] = __builtin_amdgcn_mfma_f32_16x16x32_bf16(A5[1][kt], Bp[kt], acc[1], 0, 0, 0);
    }
    unsigned short* orow = hid + (bd9216 + (size_t)w * 96 + h0 + n) * 128;
#pragma unroll
    for (int mi = 0; mi < 2; ++mi) {
      short4v pk;
#pragma unroll
      for (int r = 0; r < 4; ++r) {
        float v = acc[mi][r];
        v = v > 0.f ? v : 0.f;
        pk[r] = (short)f2bf(v);
      }
      int coff = (wave * 2 + mi) * 16 + quad * 4;
      *(short4v*)&prevs[n * 136 + coff] = pk;
      *(short4v*)(orow + coff) = pk;
    }
    __syncthreads();
  }
}

// ---------------- out = x + hid (transpose back, coalesced writes) ----------------
__global__ __launch_bounds__(256) void out_kernel(
    const float* __restrict__ x, const unsigned short* __restrict__ hid,
    float* __restrict__ out) {
  __shared__ float tile[384 * 33];
  int bid = blockIdx.x;
  int cc = bid & 3;
  int rest = bid >> 2;
  int h = rest % 96;
  int b = rest / 96;
  int c0 = cc * 32;
  int tid = threadIdx.x;
  // gather hid[b][d][w][h][c0+i]
  for (int idx = tid; idx < 32 * 384; idx += 256) {
    int i = idx & 31;
    int q = idx >> 5;
    int d = q / 96;
    int w = q % 96;
    unsigned short hv = hid[(((size_t)(b * 4 + d) * 96 + w) * 96 + h) * 128 + c0 + i];
    tile[(w * 4 + d) * 33 + i] = bf2f(hv);
  }
  __syncthreads();
  // coalesced x read + out write over (w,d)
  for (int idx = tid; idx < 32 * 384; idx += 256) {
    int c = idx / 384;
    int wd = idx % 384;
    size_t o = ((size_t)(b * 128 + c0 + c) * 96 + h) * 384 + wd;
    out[o] = x[o] + tile[wd * 33 + c];
  }
}

extern "C" void kernel_launch(void* const* d_in, const int* in_sizes, int n_in,
                              void* d_out, int out_size, void* d_ws, size_t ws_size,
                              hipStream_t stream) {
  (void)in_sizes; (void)n_in; (void)out_size; (void)ws_size;
  const float* x  = (const float*)d_in[0];
  const float* W1 = (const float*)d_in[1];
  const float* b1 = (const float*)d_in[2];
  const float* W2 = (const float*)d_in[3];
  const float* b2 = (const float*)d_in[4];
  const float* W4 = (const float*)d_in[5];
  const float* b4 = (const float*)d_in[6];
  const float* W5 = (const float*)d_in[7];
  const float* b5 = (const float*)d_in[8];
  float* out = (float*)d_out;

  char* ws = (char*)d_ws;
  unsigned short* Wb   = (unsigned short*)(ws);             // 524288 B
  float* bs12          = (float*)(ws + 524288);             // 2048 B
  float* bs45          = (float*)(ws + 526336);             // 2048 B
  unsigned short* hs   = (unsigned short*)(ws + 528384);    // 75497472 B
  unsigned short* xT   = (unsigned short*)(ws + 76025856);  // 75497472 B (reused as hid)
  unsigned short* hid  = xT;

  prep_kernel<<<(4 * 65536 + 1024 + 255) / 256, 256, 0, stream>>>(
      W1, b1, W2, b2, W4, b4, W5, b5, Wb, bs12, bs45);
  transpose_kernel<<<8 * 96 * 4, 256, 0, stream>>>(x, xT);
  row_kernel<<<192, 256, 0, stream>>>(xT, hs, Wb, bs12);
  col_kernel<<<192, 256, 0, stream>>>(hs, hid, Wb, bs45);
  out_kernel<<<8 * 96 * 4, 256, 0, stream>>>(x, hid, out);
}

// Round 2
// 495.253 us; speedup vs baseline: 1.3265x; 1.3265x over previous
//
#include <hip/hip_runtime.h>

// B=8, C=128, H=96, W=96, D=4
// xT  (ws): [b][d][h][w][c] bf16
// hs  (ws): [b][d][h][w][c] bf16
// hid (ws): [b][d][h][w][c] bf16 (reuses xT buffer)

typedef short bf16x8 __attribute__((ext_vector_type(8)));
typedef short short4v __attribute__((ext_vector_type(4)));
typedef float f32x4 __attribute__((ext_vector_type(4)));

__device__ __forceinline__ unsigned short f2bf(float f) {
  unsigned int u = __builtin_bit_cast(unsigned int, f);
  u = (u + 0x7FFFu + ((u >> 16) & 1u)) >> 16;
  return (unsigned short)u;
}
__device__ __forceinline__ float bf2f(unsigned short h) {
  unsigned int u = ((unsigned int)h) << 16;
  return __builtin_bit_cast(float, u);
}

// LDS barrier WITHOUT vmcnt(0) drain: only waits LDS ops, leaves global
// prefetch loads / fire-and-forget stores in flight across the barrier.
#define LDS_BARRIER() asm volatile("s_waitcnt lgkmcnt(0)\n\ts_barrier" ::: "memory")

// ---------------- prep: cast weights to bf16, sum biases ----------------
__global__ __launch_bounds__(256) void prep_kernel(
    const float* __restrict__ W1, const float* __restrict__ b1,
    const float* __restrict__ W2, const float* __restrict__ b2,
    const float* __restrict__ W4, const float* __restrict__ b4,
    const float* __restrict__ W5, const float* __restrict__ b5,
    unsigned short* __restrict__ Wb, float* __restrict__ bs12,
    float* __restrict__ bs45) {
  int gid = blockIdx.x * 256 + threadIdx.x;
  if (gid < 4 * 65536) {
    int m = gid >> 16;
    int r = gid & 65535;
    const float* src = (m == 0) ? W1 : (m == 1) ? W2 : (m == 2) ? W4 : W5;
    Wb[m * 65536 + r] = f2bf(src[r]);
  } else if (gid < 4 * 65536 + 512) {
    int r = gid - 4 * 65536;
    bs12[r] = b1[r] + b2[r];
  } else if (gid < 4 * 65536 + 1024) {
    int r = gid - 4 * 65536 - 512;
    bs45[r] = b4[r] + b5[r];
  }
}

// ---------------- transpose x -> xT bf16 [b][d][h][w][c] ----------------
// block = (b, h, w-half). XOR-swizzled LDS tile: rows c (128), cols wd (192 of 208).
__global__ __launch_bounds__(256) void transpose_kernel(
    const float* __restrict__ x, unsigned short* __restrict__ xT) {
  __shared__ unsigned short tile[128 * 208];
  int bid = blockIdx.x;
  int half = bid & 1;
  int rest = bid >> 1;
  int h = rest % 96;
  int b = rest / 96;
  int wd0 = half * 192;
  int tid = threadIdx.x;
  // gather: x rows, 768-B contiguous runs, write b128 swizzled rows
#pragma unroll
  for (int it = 0; it < 12; ++it) {
    int cid = it * 256 + tid;
    int c = cid / 24;
    int k = cid % 24;
    const float* xp = x + ((size_t)(b * 128 + c) * 96 + h) * 384 + wd0 + k * 8;
    float4 v0 = *(const float4*)xp;
    float4 v1 = *(const float4*)(xp + 4);
    bf16x8 pk;
    pk[0] = (short)f2bf(v0.x); pk[1] = (short)f2bf(v0.y);
    pk[2] = (short)f2bf(v0.z); pk[3] = (short)f2bf(v0.w);
    pk[4] = (short)f2bf(v1.x); pk[5] = (short)f2bf(v1.y);
    pk[6] = (short)f2bf(v1.z); pk[7] = (short)f2bf(v1.w);
    int ks = k ^ ((c >> 3) & 7);
    *(bf16x8*)&tile[c * 208 + ks * 8] = pk;
  }
  __syncthreads();
  // scatter: column-gather 8 c per thread, 256-B contiguous xT writes
#pragma unroll
  for (int it = 0; it < 12; ++it) {
    int sid = it * 256 + tid;
    int wdl = sid >> 4;
    int cc = sid & 15;
    int c0 = cc * 8;
    int k = wdl >> 3, off = wdl & 7;
    bf16x8 pk;
#pragma unroll
    for (int j = 0; j < 8; ++j) {
      int c = c0 + j;
      int ks = k ^ ((c >> 3) & 7);
      pk[j] = (short)tile[c * 208 + ks * 8 + off];
    }
    int wdg = wd0 + wdl;
    int d = wdg & 3, w = wdg >> 2;
    *(bf16x8*)(xT + ((((size_t)(b * 4 + d) * 96 + h) * 96 + w) * 128 + c0)) = pk;
  }
}

// ---------------- row scan ----------------
__global__ __launch_bounds__(256) void row_kernel(
    const unsigned short* __restrict__ xT, unsigned short* __restrict__ hs,
    const unsigned short* __restrict__ Wb, const float* __restrict__ bs12) {
  int bid = blockIdx.x;
  int wt = bid % 6;
  int bd = bid / 6;  // b*4+d
  int d = bd & 3;
  int w0 = wt * 16;
  int tid = threadIdx.x;
  int lane = tid & 63;
  int wave = tid >> 6;
  int quad = lane >> 4;
  int n = lane & 15;

  __shared__ unsigned short prevs[2][16 * 136];

  const unsigned short* w1p = Wb + d * 16384;
  const unsigned short* w2p = Wb + 65536 + d * 16384;

  bf16x8 A1[2][4], A2[2][4];
#pragma unroll
  for (int mi = 0; mi < 2; ++mi) {
    int c = (wave * 2 + mi) * 16 + n;
#pragma unroll
    for (int kt = 0; kt < 4; ++kt) {
      int k0 = kt * 32 + quad * 8;
      A1[mi][kt] = *(const bf16x8*)(w1p + c * 128 + k0);
      A2[mi][kt] = *(const bf16x8*)(w2p + c * 128 + k0);
    }
  }
  f32x4 bias[2];
#pragma unroll
  for (int mi = 0; mi < 2; ++mi)
#pragma unroll
    for (int r = 0; r < 4; ++r)
      bias[mi][r] = bs12[d * 128 + (wave * 2 + mi) * 16 + quad * 4 + r];

  size_t bd9216 = (size_t)bd * 9216;

  // h = 0 seed: hs row 0 = x row 0
  {
    int wl = tid >> 4;
    int c8 = (tid & 15) * 8;
    bf16x8 v = *(const bf16x8*)(xT + (bd9216 + (size_t)(w0 + wl)) * 128 + c8);
    *(bf16x8*)&prevs[0][wl * 136 + c8] = v;
    *(bf16x8*)(hs + (bd9216 + (size_t)(w0 + wl)) * 128 + c8) = v;
  }

  // prefetch x rows 1,2,3; compute accA for h=1
  bf16x8 Bt[4], Bn[4], Bf[4];
  {
    const unsigned short* p1 = xT + (bd9216 + (size_t)1 * 96 + w0 + n) * 128;
    const unsigned short* p2 = xT + (bd9216 + (size_t)2 * 96 + w0 + n) * 128;
    const unsigned short* p3 = xT + (bd9216 + (size_t)3 * 96 + w0 + n) * 128;
#pragma unroll
    for (int kt = 0; kt < 4; ++kt) {
      int k0 = kt * 32 + quad * 8;
      Bt[kt] = *(const bf16x8*)(p1 + k0);
      Bn[kt] = *(const bf16x8*)(p2 + k0);
      Bf[kt] = *(const bf16x8*)(p3 + k0);
    }
  }
  f32x4 accA[2] = {bias[0], bias[1]};
#pragma unroll
  for (int kt = 0; kt < 4; ++kt) {
    accA[0] = __builtin_amdgcn_mfma_f32_16x16x32_bf16(A1[0][kt], Bt[kt], accA[0], 0, 0, 0);
    accA[1] = __builtin_amdgcn_mfma_f32_16x16x32_bf16(A1[1][kt], Bt[kt], accA[1], 0, 0, 0);
  }

  for (int h = 1; h < 96; ++h) {
    LDS_BARRIER();
    const unsigned short* pr = &prevs[(h - 1) & 1][n * 136];
    bf16x8 Bp[4];
#pragma unroll
    for (int kt = 0; kt < 4; ++kt)
      Bp[kt] = *(const bf16x8*)(pr + kt * 32 + quad * 8);
    f32x4 acc0 = accA[0], acc1 = accA[1];
#pragma unroll
    for (int kt = 0; kt < 4; ++kt) {
      acc0 = __builtin_amdgcn_mfma_f32_16x16x32_bf16(A2[0][kt], Bp[kt], acc0, 0, 0, 0);
      acc1 = __builtin_amdgcn_mfma_f32_16x16x32_bf16(A2[1][kt], Bp[kt], acc1, 0, 0, 0);
    }
    // relu + pack + write (LDS next-buf + global hs)
    unsigned short* pw = &prevs[h & 1][n * 136];
    unsigned short* hrow = hs + (bd9216 + (size_t)h * 96 + w0 + n) * 128;
    short4v pk0, pk1;
#pragma unroll
    for (int r = 0; r < 4; ++r) {
      float v = acc0[r]; v = v > 0.f ? v : 0.f; pk0[r] = (short)f2bf(v);
      float u = acc1[r]; u = u > 0.f ? u : 0.f; pk1[r] = (short)f2bf(u);
    }
    int co0 = (wave * 2 + 0) * 16 + quad * 4;
    int co1 = (wave * 2 + 1) * 16 + quad * 4;
    *(short4v*)(pw + co0) = pk0;
    *(short4v*)(pw + co1) = pk1;
    *(short4v*)(hrow + co0) = pk0;
    *(short4v*)(hrow + co1) = pk1;
    // accA for step h+1 (overlaps next barrier + ds_read)
    accA[0] = bias[0]; accA[1] = bias[1];
#pragma unroll
    for (int kt = 0; kt < 4; ++kt) {
      accA[0] = __builtin_amdgcn_mfma_f32_16x16x32_bf16(A1[0][kt], Bn[kt], accA[0], 0, 0, 0);
      accA[1] = __builtin_amdgcn_mfma_f32_16x16x32_bf16(A1[1][kt], Bn[kt], accA[1], 0, 0, 0);
    }
    // rotate + prefetch h+3 (2-iteration latency cover)
    int hp = (h + 3 <= 95) ? h + 3 : 95;
    const unsigned short* pf = xT + (bd9216 + (size_t)hp * 96 + w0 + n) * 128;
#pragma unroll
    for (int kt = 0; kt < 4; ++kt) {
      Bn[kt] = Bf[kt];
      Bf[kt] = *(const bf16x8*)(pf + kt * 32 + quad * 8);
    }
  }
}

// ---------------- col scan: hid[b][d][h][w][c] ----------------
__global__ __launch_bounds__(256) void col_kernel(
    const unsigned short* __restrict__ hs, unsigned short* __restrict__ hid,
    const unsigned short* __restrict__ Wb, const float* __restrict__ bs45) {
  int bid = blockIdx.x;
  int ht = bid % 6;
  int bd = bid / 6;
  int d = bd & 3;
  int h0 = ht * 16;
  int tid = threadIdx.x;
  int lane = tid & 63;
  int wave = tid >> 6;
  int quad = lane >> 4;
  int n = lane & 15;

  __shared__ unsigned short prevs[2][16 * 136];

  const unsigned short* w4p = Wb + 2 * 65536 + d * 16384;
  const unsigned short* w5p = Wb + 3 * 65536 + d * 16384;

  bf16x8 A4[2][4], A5[2][4];
#pragma unroll
  for (int mi = 0; mi < 2; ++mi) {
    int c = (wave * 2 + mi) * 16 + n;
#pragma unroll
    for (int kt = 0; kt < 4; ++kt) {
      int k0 = kt * 32 + quad * 8;
      A4[mi][kt] = *(const bf16x8*)(w4p + c * 128 + k0);
      A5[mi][kt] = *(const bf16x8*)(w5p + c * 128 + k0);
    }
  }
  f32x4 bias[2];
#pragma unroll
  for (int mi = 0; mi < 2; ++mi)
#pragma unroll
    for (int r = 0; r < 4; ++r)
      bias[mi][r] = bs45[d * 128 + (wave * 2 + mi) * 16 + quad * 4 + r];

  size_t bd9216 = (size_t)bd * 9216;

  // w = 0 seed: hid col 0 = relu(hs col 0)
  {
    int hl = tid >> 4;
    int c8 = (tid & 15) * 8;
    size_t base = (bd9216 + (size_t)(h0 + hl) * 96) * 128 + c8;
    bf16x8 v = *(const bf16x8*)(hs + base);
#pragma unroll
    for (int j = 0; j < 8; ++j) {
      unsigned short uv = (unsigned short)v[j];
      if (uv & 0x8000u) v[j] = 0;  // bf16 relu
    }
    *(bf16x8*)&prevs[0][hl * 136 + c8] = v;
    *(bf16x8*)(hid + base) = v;
  }

  bf16x8 Bt[4], Bn[4], Bf[4];
  {
    const unsigned short* p1 = hs + (bd9216 + (size_t)(h0 + n) * 96 + 1) * 128;
    const unsigned short* p2 = hs + (bd9216 + (size_t)(h0 + n) * 96 + 2) * 128;
    const unsigned short* p3 = hs + (bd9216 + (size_t)(h0 + n) * 96 + 3) * 128;
#pragma unroll
    for (int kt = 0; kt < 4; ++kt) {
      int k0 = kt * 32 + quad * 8;
      Bt[kt] = *(const bf16x8*)(p1 + k0);
      Bn[kt] = *(const bf16x8*)(p2 + k0);
      Bf[kt] = *(const bf16x8*)(p3 + k0);
    }
  }
  f32x4 accA[2] = {bias[0], bias[1]};
#pragma unroll
  for (int kt = 0; kt < 4; ++kt) {
    accA[0] = __builtin_amdgcn_mfma_f32_16x16x32_bf16(A4[0][kt], Bt[kt], accA[0], 0, 0, 0);
    accA[1] = __builtin_amdgcn_mfma_f32_16x16x32_bf16(A4[1][kt], Bt[kt], accA[1], 0, 0, 0);
  }

  for (int w = 1; w < 96; ++w) {
    LDS_BARRIER();
    const unsigned short* pr = &prevs[(w - 1) & 1][n * 136];
    bf16x8 Bp[4];
#pragma unroll
    for (int kt = 0; kt < 4; ++kt)
      Bp[kt] = *(const bf16x8*)(pr + kt * 32 + quad * 8);
    f32x4 acc0 = accA[0], acc1 = accA[1];
#pragma unroll
    for (int kt = 0; kt < 4; ++kt) {
      acc0 = __builtin_amdgcn_mfma_f32_16x16x32_bf16(A5[0][kt], Bp[kt], acc0, 0, 0, 0);
      acc1 = __builtin_amdgcn_mfma_f32_16x16x32_bf16(A5[1][kt], Bp[kt], acc1, 0, 0, 0);
    }
    unsigned short* pw = &prevs[w & 1][n * 136];
    unsigned short* orow = hid + (bd9216 + (size_t)(h0 + n) * 96 + w) * 128;
    short4v pk0, pk1;
#pragma unroll
    for (int r = 0; r < 4; ++r) {
      float v = acc0[r]; v = v > 0.f ? v : 0.f; pk0[r] = (short)f2bf(v);
      float u = acc1[r]; u = u > 0.f ? u : 0.f; pk1[r] = (short)f2bf(u);
    }
    int co0 = (wave * 2 + 0) * 16 + quad * 4;
    int co1 = (wave * 2 + 1) * 16 + quad * 4;
    *(short4v*)(pw + co0) = pk0;
    *(short4v*)(pw + co1) = pk1;
    *(short4v*)(orow + co0) = pk0;
    *(short4v*)(orow + co1) = pk1;
    accA[0] = bias[0]; accA[1] = bias[1];
#pragma unroll
    for (int kt = 0; kt < 4; ++kt) {
      accA[0] = __builtin_amdgcn_mfma_f32_16x16x32_bf16(A4[0][kt], Bn[kt], accA[0], 0, 0, 0);
      accA[1] = __builtin_amdgcn_mfma_f32_16x16x32_bf16(A4[1][kt], Bn[kt], accA[1], 0, 0, 0);
    }
    int wp = (w + 3 <= 95) ? w + 3 : 95;
    const unsigned short* pf = hs + (bd9216 + (size_t)(h0 + n) * 96 + wp) * 128;
#pragma unroll
    for (int kt = 0; kt < 4; ++kt) {
      Bn[kt] = Bf[kt];
      Bf[kt] = *(const bf16x8*)(pf + kt * 32 + quad * 8);
    }
  }
}

// ---------------- out = x + hid (mirror of transpose) ----------------
__global__ __launch_bounds__(256) void out_kernel(
    const float* __restrict__ x, const unsigned short* __restrict__ hid,
    float* __restrict__ out) {
  __shared__ unsigned short tile[128 * 208];
  int bid = blockIdx.x;
  int half = bid & 1;
  int rest = bid >> 1;
  int h = rest % 96;
  int b = rest / 96;
  int wd0 = half * 192;
  int tid = threadIdx.x;
  // gather hid: 256-B contiguous reads, column-scatter into swizzled tile
#pragma unroll
  for (int it = 0; it < 12; ++it) {
    int gid = it * 256 + tid;
    int wdl = gid >> 4;
    int cc = gid & 15;
    int c0 = cc * 8;
    int wdg = wd0 + wdl;
    int d = wdg & 3, w = wdg >> 2;
    bf16x8 v = *(const bf16x8*)(hid + ((((size_t)(b * 4 + d) * 96 + h) * 96 + w) * 128 + c0));
    int k = wdl >> 3, off = wdl & 7;
#pragma unroll
    for (int j = 0; j < 8; ++j) {
      int c = c0 + j;
      int ks = k ^ ((c >> 3) & 7);
      tile[c * 208 + ks * 8 + off] = (unsigned short)v[j];
    }
  }
  __syncthreads();
  // scatter: b128 row reads, float4 x/out with 768-B runs
#pragma unroll
  for (int it = 0; it < 12; ++it) {
    int sid = it * 256 + tid;
    int c = sid / 24;
    int k = sid % 24;
    int ks = k ^ ((c >> 3) & 7);
    bf16x8 pk = *(const bf16x8*)&tile[c * 208 + ks * 8];
    size_t o = ((size_t)(b * 128 + c) * 96 + h) * 384 + wd0 + k * 8;
    float4 a0 = *(const float4*)(x + o);
    float4 a1 = *(const float4*)(x + o + 4);
    float4 r0, r1;
    r0.x = a0.x + bf2f((unsigned short)pk[0]);
    r0.y = a0.y + bf2f((unsigned short)pk[1]);
    r0.z = a0.z + bf2f((unsigned short)pk[2]);
    r0.w = a0.w + bf2f((unsigned short)pk[3]);
    r1.x = a1.x + bf2f((unsigned short)pk[4]);
    r1.y = a1.y + bf2f((unsigned short)pk[5]);
    r1.z = a1.z + bf2f((unsigned short)pk[6]);
    r1.w = a1.w + bf2f((unsigned short)pk[7]);
    *(float4*)(out + o) = r0;
    *(float4*)(out + o + 4) = r1;
  }
}

extern "C" void kernel_launch(void* const* d_in, const int* in_sizes, int n_in,
                              void* d_out, int out_size, void* d_ws, size_t ws_size,
                              hipStream_t stream) {
  (void)in_sizes; (void)n_in; (void)out_size; (void)ws_size;
  const float* x  = (const float*)d_in[0];
  const float* W1 = (const float*)d_in[1];
  const float* b1 = (const float*)d_in[2];
  const float* W2 = (const float*)d_in[3];
  const float* b2 = (const float*)d_in[4];
  const float* W4 = (const float*)d_in[5];
  const float* b4 = (const float*)d_in[6];
  const float* W5 = (const float*)d_in[7];
  const float* b5 = (const float*)d_in[8];
  float* out = (float*)d_out;

  char* ws = (char*)d_ws;
  unsigned short* Wb   = (unsigned short*)(ws);             // 524288 B
  float* bs12          = (float*)(ws + 524288);             // 2048 B
  float* bs45          = (float*)(ws + 526336);             // 2048 B
  unsigned short* hs   = (unsigned short*)(ws + 528384);    // 75497472 B
  unsigned short* xT   = (unsigned short*)(ws + 76025856);  // 75497472 B (reused as hid)
  unsigned short* hid  = xT;

  prep_kernel<<<(4 * 65536 + 1024 + 255) / 256, 256, 0, stream>>>(
      W1, b1, W2, b2, W4, b4, W5, b5, Wb, bs12, bs45);
  transpose_kernel<<<8 * 96 * 2, 256, 0, stream>>>(x, xT);
  row_kernel<<<192, 256, 0, stream>>>(xT, hs, Wb, bs12);
  col_kernel<<<192, 256, 0, stream>>>(hs, hid, Wb, bs45);
  out_kernel<<<8 * 96 * 2, 256, 0, stream>>>(x, hid, out);
}